// Round 3
// baseline (24938.300 us; speedup 1.0000x reference)
//
#include <hip/hip_runtime.h>
#include <stdint.h>

// B=64, L=128, H=512, LAB=128. 8192 strictly-sequential LSTM cell steps
// sharing one (h,c) of size 512:
//   gates[s] = pre[s] + W_p @ h[s-64] + W_hh @ h[s-1]
//   pre[s]   = W_ih[:, :2048] @ [x;hi] + b_ih + b_hh     (parallel GEMM)
//
// ws layout (needs 48MB + 4KB):
//   [0,32MB)   pre32: bf16-pair-packed u32 [8192][1024]  ([s][g*256 + j>>1])
//   [32,48MB)  units: u32 [8192][512], unit = (tag16 << 16) | bf16(h[j])
//              tag = step+1 (1..8192); 0xAA poison tag 0xAAAA never aliases.
//   [48MB]     ctrl[0]: done counter (poison-relative; +1 per clean WG)
//
// R8: R7 proved contention is NOT the bottleneck (4x fewer poll reads ->
// slower; barriers cost ~2100cy/step) but validated the done-ctr/chaser
// interop. Step decomposition of the proven 4080cy kernel: ~1800cy
// visibility+RT+compute, ~2x950cy sampling quantization (poll trip period
// enters twice: producer publish spread + consumer last-line discovery).
// lstm_seq3 = proven wave-independent kernel with 4 phase-spaced poll
// snapshots (s_sleep(3) spacers, per-batch vmcnt via compiler dataflow):
// sampling granularity ~950 -> ~250-320cy. Math/tags/ownership identical.
// On exhaust: halt WITHOUT publishing; chaser (unchanged, proven) redoes.

#define HDIM   512
#define NSTEP  8192
#define XDIM   2048
#define IN5H   2560
#define LSEQ   128
#define LAB    128
#define SPIN_LIMIT 65536
#define POLL_LIMIT 4096
#define USPIN_LIMIT 16384
#define TAGMASK 0xFFFF0000FFFF0000ULL

typedef float f32x4 __attribute__((ext_vector_type(4)));
typedef short bf16x8 __attribute__((ext_vector_type(8)));

__device__ __forceinline__ unsigned f2bf(float v){
  unsigned u = __float_as_uint(v);
  u += 0x7fffu + ((u >> 16) & 1u);      // RNE; values bounded (no NaN/Inf)
  return u >> 16;
}
__device__ __forceinline__ float bfu(unsigned half16){   // bf16 bits -> f32
  return __uint_as_float(half16 << 16);
}
template<int CTRL>
__device__ __forceinline__ float dpp_add(float x){
  const int yi = __builtin_amdgcn_update_dpp(0, __float_as_int(x), CTRL, 0xF, 0xF, true);
  return x + __int_as_float(yi);
}
// sum of x across 64 lanes, valid in lane 63 (other lanes partial)
__device__ __forceinline__ float wave_reduce63(float x){
  x = dpp_add<0x111>(x);   // row_shr:1
  x = dpp_add<0x112>(x);   // row_shr:2
  x = dpp_add<0x114>(x);   // row_shr:4
  x = dpp_add<0x118>(x);   // row_shr:8  -> lane15+16k = row sum
  x = dpp_add<0x142>(x);   // row_bcast:15
  x = dpp_add<0x143>(x);   // row_bcast:31 -> lane 63 = total
  return x;
}

// ---------------------------------------------------------------- phase 1
// pre[s][r] = sum_k xcat[s][k]*W_ih[r][k] + b_ih[r] + b_hh[r], bf16-packed.
__global__ __launch_bounds__(256) void gemm_pre(
    const float* __restrict__ x, const float* __restrict__ hi,
    const float* __restrict__ Wih, const float* __restrict__ bih,
    const float* __restrict__ bhh, unsigned* __restrict__ pre32)
{
  __shared__ unsigned short As[128][40];   // +8 pad, 16B-aligned b128 reads
  __shared__ unsigned short Bs[128][40];
  const int tid = threadIdx.x;
  const int bm = blockIdx.x, bn = blockIdx.y;
  const int lane = tid & 63, wv = tid >> 6;
  const int wm = wv & 1, wn = wv >> 1;

  const int srow = tid >> 1;              // staging row 0..127
  const int ch   = (tid & 1) * 16;        // col half of the 32-wide K chunk

  const int gr = bm*128 + srow;           // global s row
  const int bb = gr & 63, tt = gr >> 6;   // s = t*64 + b
  const float* ax = x  + (size_t)(bb*LSEQ + tt) * 1024;
  const float* ah = hi + (size_t)(bb*LSEQ + tt) * 1024;
  const int R = bn*128 + srow;            // global gate row
  const float* bw = Wih + (size_t)R * IN5H;

  f32x4 acc[4][4];
  #pragma unroll
  for (int m=0;m<4;++m)
    #pragma unroll
    for (int n=0;n<4;++n) acc[m][n] = (f32x4){0.f,0.f,0.f,0.f};

  for (int kc = 0; kc < XDIM; kc += 32){
    const int c0 = kc + ch;
    const float* ap = (c0 < 1024) ? (ax + c0) : (ah + (c0 - 1024));
    #pragma unroll
    for (int q=0;q<4;++q){
      float4 va = *(const float4*)(ap + 4*q);
      float4 vb = *(const float4*)(bw + c0 + 4*q);
      ushort4 ua; ua.x=f2bf(va.x); ua.y=f2bf(va.y); ua.z=f2bf(va.z); ua.w=f2bf(va.w);
      ushort4 ub; ub.x=f2bf(vb.x); ub.y=f2bf(vb.y); ub.z=f2bf(vb.z); ub.w=f2bf(vb.w);
      *(ushort4*)&As[srow][ch + 4*q] = ua;
      *(ushort4*)&Bs[srow][ch + 4*q] = ub;
    }
    __syncthreads();
    bf16x8 afr[4], bfr[4];
    const int mr = wm*64 + (lane & 15);
    const int nr = wn*64 + (lane & 15);
    const int ko = (lane >> 4) * 8;
    #pragma unroll
    for (int m=0;m<4;++m) afr[m] = *(const bf16x8*)&As[mr + 16*m][ko];
    #pragma unroll
    for (int n=0;n<4;++n) bfr[n] = *(const bf16x8*)&Bs[nr + 16*n][ko];
    #pragma unroll
    for (int m=0;m<4;++m)
      #pragma unroll
      for (int n=0;n<4;++n)
        acc[m][n] = __builtin_amdgcn_mfma_f32_16x16x32_bf16(afr[m], bfr[n], acc[m][n], 0, 0, 0);
    __syncthreads();
  }
  // C/D layout: col = lane&15 (N side), row = (lane>>4)*4+q (M side)
  #pragma unroll
  for (int n=0;n<4;++n){
    const int scol = bn*128 + wn*64 + 16*n + (lane & 15);
    const float bias = bih[scol] + bhh[scol];
    #pragma unroll
    for (int m=0;m<4;++m){
      const int sr0 = bm*128 + wm*64 + 16*m + (lane >> 4)*4;
      #pragma unroll
      for (int q=0;q<4;++q){
        const float v = acc[m][n][q] + bias;
        const float vn = __shfl_xor(v, 1, 64);     // neighbor col (scol^1)
        if (!(lane & 1)){
          const unsigned word = f2bf(v) | (f2bf(vn) << 16);
          pre32[(size_t)(sr0 + q) * 1024 + (scol >> 1)] = word;
        }
      }
    }
  }
}

#define ISSUE4(v0,v1,v2,v3,bp) do{ \
  v0 = __hip_atomic_load((bp)+0,   __ATOMIC_RELAXED, __HIP_MEMORY_SCOPE_AGENT); \
  v1 = __hip_atomic_load((bp)+64,  __ATOMIC_RELAXED, __HIP_MEMORY_SCOPE_AGENT); \
  v2 = __hip_atomic_load((bp)+128, __ATOMIC_RELAXED, __HIP_MEMORY_SCOPE_AGENT); \
  v3 = __hip_atomic_load((bp)+192, __ATOMIC_RELAXED, __HIP_MEMORY_SCOPE_AGENT); \
}while(0)
#define MATCH4(v0,v1,v2,v3,wq) \
  (__all((((((v0)^(wq))|((v1)^(wq))|((v2)^(wq))|((v3)^(wq))) & TAGMASK) == 0) ? 1 : 0))

// ---------------------------------------------------------------- phase 2a
// Phase-spaced-poll sequencer. Identical ownership/layout/math to the
// proven lstm_seq: 128 WGs x 4 waves, wave owns j0, lane l holds u64 words
// {l,l+64,l+128,l+192} of each 2KB row; weight col(k)=2l+128(k>>1)+(k&1).
// Poll keeps 4 snapshot batches in flight, re-issued round-robin with
// s_sleep(3) (~192cy) spacers -> sampling granularity ~250-320cy instead
// of ~950cy (one blocking trip). Compiler's per-register vmcnt tracking
// makes each MATCH wait only for its own batch (proven by the existing
// prefetch-overlap pattern). On exhaust: halt WITHOUT publishing; the
// chaser redoes all work (prefix in units is bit-identical).
__global__ __launch_bounds__(256)
__attribute__((amdgpu_waves_per_eu(1,1)))
void lstm_seq3(
    const float* __restrict__ Wih, const float* __restrict__ Whh,
    const unsigned* __restrict__ pre32, unsigned* __restrict__ units,
    unsigned* __restrict__ ctrl)
{
  __shared__ int sh_bad;
  const int tid = threadIdx.x;
  const int l = tid & 63;
  const int j0 = blockIdx.x * 4 + (tid >> 6);      // 0..511
  if (tid == 0) sh_bad = 0;
  __syncthreads();

  // ---- weights into VGPRs (once): col(k) = 2l + 128*(k>>1) + (k&1) ----
  float wh[4][8], wu[4][8];
  #pragma unroll
  for (int g=0; g<4; ++g){
    const float* ph = Whh + (size_t)(g*HDIM + j0)*HDIM;
    const float* pu = Wih + (size_t)(g*HDIM + j0)*IN5H + XDIM;
    #pragma unroll
    for (int k=0; k<8; ++k){
      const int col = 2*l + 128*(k>>1) + (k&1);
      wh[g][k] = ph[col]; wu[g][k] = pu[col];
    }
  }
  #pragma unroll
  for (int g=0; g<4; ++g)
    #pragma unroll
    for (int k=0; k<8; ++k){
      asm volatile("" : "+v"(wh[g][k]));
      asm volatile("" : "+v"(wu[g][k]));
    }

  const int phalf = j0 >> 1, psel = j0 & 1;
  float pr[4];
  #pragma unroll
  for (int g=0; g<4; ++g){
    const unsigned w0 = pre32[(size_t)0*1024 + g*256 + phalf];
    pr[g] = psel ? bfu(w0 >> 16) : bfu(w0 & 0xffffu);
  }

  float uvc[8];
  #pragma unroll
  for (int k=0;k<8;++k) uvc[k] = 0.f;

  float cst = 0.f;
  int dead = 0;

  for (int s = 0; s < NSTEP; ++s){
    // ---- prefetches (overlap the poll RT window) ----
    unsigned pw[4];
    const bool pf  = (s + 1 < NSTEP);
    const bool upf = (s + 1 >= 64) && pf;
    if (pf){
      #pragma unroll
      for (int g=0; g<4; ++g)
        pw[g] = pre32[(size_t)(s+1)*1024 + g*256 + phalf];
    }
    unsigned long long un[4];
    if (upf){
      const unsigned long long* bp =
          (const unsigned long long*)(units + (size_t)(s-63)*HDIM) + l;
      #pragma unroll
      for (int c=0;c<4;++c)
        un[c] = __hip_atomic_load(bp + 64*c, __ATOMIC_RELAXED, __HIP_MEMORY_SCOPE_AGENT);
    }

    // ---- poll h[s-1]: 4 phase-spaced snapshot batches ----
    float hv[8];
    if (s == 0){
      #pragma unroll
      for (int k=0;k<8;++k) hv[k] = 0.f;
    } else {
      const unsigned long long* bp =
          (const unsigned long long*)(units + (size_t)(s-1)*HDIM) + l;
      const unsigned long long wq =
          ((unsigned long long)(unsigned)s << 16) |
          ((unsigned long long)(unsigned)s << 48);
      unsigned long long A0,A1,A2,A3,B0,B1,B2,B3,C0,C1,C2,C3,D0,D1,D2,D3;
      unsigned long long h0,h1,h2,h3;
      ISSUE4(A0,A1,A2,A3,bp);
      ISSUE4(B0,B1,B2,B3,bp);
      __builtin_amdgcn_s_sleep(3);
      ISSUE4(C0,C1,C2,C3,bp);
      __builtin_amdgcn_s_sleep(3);
      ISSUE4(D0,D1,D2,D3,bp);
      int got = 0, iters = 0;
      do {
        if (MATCH4(A0,A1,A2,A3,wq)){ h0=A0;h1=A1;h2=A2;h3=A3; got=1; break; }
        ISSUE4(A0,A1,A2,A3,bp);
        __builtin_amdgcn_s_sleep(3);
        if (MATCH4(B0,B1,B2,B3,wq)){ h0=B0;h1=B1;h2=B2;h3=B3; got=1; break; }
        ISSUE4(B0,B1,B2,B3,bp);
        __builtin_amdgcn_s_sleep(3);
        if (MATCH4(C0,C1,C2,C3,wq)){ h0=C0;h1=C1;h2=C2;h3=C3; got=1; break; }
        ISSUE4(C0,C1,C2,C3,bp);
        __builtin_amdgcn_s_sleep(3);
        if (MATCH4(D0,D1,D2,D3,wq)){ h0=D0;h1=D1;h2=D2;h3=D3; got=1; break; }
        ISSUE4(D0,D1,D2,D3,bp);
      } while (++iters < POLL_LIMIT);
      if (!got){ dead = 1; }
      if (dead){ sh_bad = 1; break; }     // halt WITHOUT publishing step s
      hv[0] = bfu((unsigned)h0 & 0xffffu);
      hv[1] = bfu((unsigned)(h0 >> 32) & 0xffffu);
      hv[2] = bfu((unsigned)h1 & 0xffffu);
      hv[3] = bfu((unsigned)(h1 >> 32) & 0xffffu);
      hv[4] = bfu((unsigned)h2 & 0xffffu);
      hv[5] = bfu((unsigned)(h2 >> 32) & 0xffffu);
      hv[6] = bfu((unsigned)h3 & 0xffffu);
      hv[7] = bfu((unsigned)(h3 >> 32) & 0xffffu);
    }

    // ---- matvec: 4 gate rows x (8 h-cols + 8 u-cols) ----
    float a0=0.f, a1=0.f, a2=0.f, a3=0.f;
    #pragma unroll
    for (int k=0;k<8;++k){
      a0 += wh[0][k]*hv[k]; a1 += wh[1][k]*hv[k];
      a2 += wh[2][k]*hv[k]; a3 += wh[3][k]*hv[k];
    }
    #pragma unroll
    for (int k=0;k<8;++k){
      a0 += wu[0][k]*uvc[k]; a1 += wu[1][k]*uvc[k];
      a2 += wu[2][k]*uvc[k]; a3 += wu[3][k]*uvc[k];
    }
    a0 = wave_reduce63(a0);
    a1 = wave_reduce63(a1);
    a2 = wave_reduce63(a2);
    a3 = wave_reduce63(a3);

    // ---- pointwise (only lane 63's chain is valid; only it publishes) ----
    float gi = a0 + pr[0];
    float gf = a1 + pr[1];
    float gg = a2 + pr[2];
    float go = a3 + pr[3];
    gi = 1.f/(1.f + __expf(-gi));
    gf = 1.f/(1.f + __expf(-gf));
    go = 1.f/(1.f + __expf(-go));
    float e2 = __expf(2.f * fminf(fmaxf(gg, -15.f), 15.f));
    gg = (e2 - 1.f) / (e2 + 1.f);
    cst = gf*cst + gi*gg;
    float e2c = __expf(2.f * fminf(fmaxf(cst, -15.f), 15.f));
    const float hval = go * ((e2c - 1.f) / (e2c + 1.f));

    if (l == 63){
      const unsigned unit = ((unsigned)(s + 1) << 16) | f2bf(hval);
      __hip_atomic_store(units + (size_t)s*HDIM + j0, unit,
                         __ATOMIC_RELAXED, __HIP_MEMORY_SCOPE_AGENT);
    }

    // ---- finalize u prefetch (off critical path; halting variant) ----
    if (upf){
      const unsigned long long uq =
          ((unsigned long long)(unsigned)(s-62) << 16) |
          ((unsigned long long)(unsigned)(s-62) << 48);
      int lok = ((((un[0]^uq)|(un[1]^uq)|(un[2]^uq)|(un[3]^uq)) & TAGMASK) == 0);
      if (!__all(lok)){
        const unsigned long long* bp =
            (const unsigned long long*)(units + (size_t)(s-63)*HDIM) + l;
        int trips = 0, ok;
        do {
          #pragma unroll
          for (int c=0;c<4;++c)
            un[c] = __hip_atomic_load(bp + 64*c, __ATOMIC_RELAXED, __HIP_MEMORY_SCOPE_AGENT);
          int lk = ((((un[0]^uq)|(un[1]^uq)|(un[2]^uq)|(un[3]^uq)) & TAGMASK) == 0);
          ok = __all(lk);
        } while (!ok && ++trips < USPIN_LIMIT);
        if (!ok){ sh_bad = 1; break; }
      }
      #pragma unroll
      for (int c=0;c<4;++c){
        uvc[2*c]   = bfu((unsigned)un[c] & 0xffffu);
        uvc[2*c+1] = bfu((unsigned)(un[c] >> 32) & 0xffffu);
      }
    } else {
      #pragma unroll
      for (int k=0;k<8;++k) uvc[k] = 0.f;
    }
    if (pf){
      #pragma unroll
      for (int g=0; g<4; ++g)
        pr[g] = psel ? bfu(pw[g] >> 16) : bfu(pw[g] & 0xffffu);
    }
  }

  __syncthreads();
  if (tid == 0 && sh_bad == 0) atomicAdd(ctrl, 1u);   // per-WG completion
}

// ---------------------------------------------------------------- phase 2b
// Global-scope proven path (chaser / legacy). Unchanged math; early-exits
// when lstm_seq3 attests full completion (done == poison + 128 WGs).
__global__ __launch_bounds__(256)
__attribute__((amdgpu_waves_per_eu(1,1)))
void lstm_seq(
    const float* __restrict__ Wih, const float* __restrict__ Whh,
    const unsigned* __restrict__ pre32, unsigned* __restrict__ units,
    const unsigned* __restrict__ done_ctrl)
{
  if (done_ctrl){
    if (*(volatile const unsigned*)done_ctrl == 0xAAAAAAAAu + 128u) return;
  }
  const int tid = threadIdx.x;
  const int l = tid & 63;
  const int j0 = blockIdx.x * 4 + (tid >> 6);      // 0..511

  // ---- weights into VGPRs (once): col(k) = 2l + 128*(k>>1) + (k&1) ----
  float wh[4][8], wu[4][8];
  #pragma unroll
  for (int g=0; g<4; ++g){
    const float* ph = Whh + (size_t)(g*HDIM + j0)*HDIM;
    const float* pu = Wih + (size_t)(g*HDIM + j0)*IN5H + XDIM;
    #pragma unroll
    for (int k=0; k<8; ++k){
      const int col = 2*l + 128*(k>>1) + (k&1);
      wh[g][k] = ph[col]; wu[g][k] = pu[col];
    }
  }
  #pragma unroll
  for (int g=0; g<4; ++g)
    #pragma unroll
    for (int k=0; k<8; ++k){
      asm volatile("" : "+v"(wh[g][k]));
      asm volatile("" : "+v"(wu[g][k]));
    }

  const int phalf = j0 >> 1, psel = j0 & 1;
  float pr[4];
  #pragma unroll
  for (int g=0; g<4; ++g){
    const unsigned w0 = pre32[(size_t)0*1024 + g*256 + phalf];
    pr[g] = psel ? bfu(w0 >> 16) : bfu(w0 & 0xffffu);
  }

  float uvc[8];
  #pragma unroll
  for (int k=0;k<8;++k) uvc[k] = 0.f;

  float cst = 0.f;
  int dead = 0;

  for (int s = 0; s < NSTEP; ++s){
    unsigned pw[4];
    const bool pf  = (s + 1 < NSTEP);
    const bool upf = (s + 1 >= 64) && pf;
    if (pf){
      #pragma unroll
      for (int g=0; g<4; ++g)
        pw[g] = pre32[(size_t)(s+1)*1024 + g*256 + phalf];
    }
    unsigned long long un[4];
    if (upf){
      const unsigned long long* bp =
          (const unsigned long long*)(units + (size_t)(s-63)*HDIM) + l;
      #pragma unroll
      for (int c=0;c<4;++c)
        un[c] = __hip_atomic_load(bp + 64*c, __ATOMIC_RELAXED, __HIP_MEMORY_SCOPE_AGENT);
    }

    float hv[8];
    if (s == 0){
      #pragma unroll
      for (int k=0;k<8;++k) hv[k] = 0.f;
    } else {
      const unsigned long long* bp =
          (const unsigned long long*)(units + (size_t)(s-1)*HDIM) + l;
      unsigned long long v[4];
      if (dead){
        #pragma unroll
        for (int c=0;c<4;++c) v[c] = __hip_atomic_load(bp + 64*c, __ATOMIC_RELAXED, __HIP_MEMORY_SCOPE_AGENT);
      } else {
        int trips = 0, ok;
        do {
          #pragma unroll
          for (int c=0;c<4;++c) v[c] = __hip_atomic_load(bp + 64*c, __ATOMIC_RELAXED, __HIP_MEMORY_SCOPE_AGENT);
          int lok = 1;
          #pragma unroll
          for (int c=0;c<4;++c){
            lok &= (((unsigned)(v[c] >> 16) & 0xffffu) == (unsigned)s);
            lok &= (((unsigned)(v[c] >> 48)) == (unsigned)s);
          }
          ok = __all(lok);
        } while (!ok && ++trips < SPIN_LIMIT);
        if (!ok) dead = 1;
      }
      #pragma unroll
      for (int c=0;c<4;++c){
        hv[2*c]   = bfu((unsigned)v[c] & 0xffffu);
        hv[2*c+1] = bfu((unsigned)(v[c] >> 32) & 0xffffu);
      }
    }

    float a0=0.f, a1=0.f, a2=0.f, a3=0.f;
    #pragma unroll
    for (int k=0;k<8;++k){
      a0 += wh[0][k]*hv[k]; a1 += wh[1][k]*hv[k];
      a2 += wh[2][k]*hv[k]; a3 += wh[3][k]*hv[k];
    }
    #pragma unroll
    for (int k=0;k<8;++k){
      a0 += wu[0][k]*uvc[k]; a1 += wu[1][k]*uvc[k];
      a2 += wu[2][k]*uvc[k]; a3 += wu[3][k]*uvc[k];
    }
    a0 = wave_reduce63(a0);
    a1 = wave_reduce63(a1);
    a2 = wave_reduce63(a2);
    a3 = wave_reduce63(a3);

    float gi = a0 + pr[0];
    float gf = a1 + pr[1];
    float gg = a2 + pr[2];
    float go = a3 + pr[3];
    gi = 1.f/(1.f + __expf(-gi));
    gf = 1.f/(1.f + __expf(-gf));
    go = 1.f/(1.f + __expf(-go));
    float e2 = __expf(2.f * fminf(fmaxf(gg, -15.f), 15.f));
    gg = (e2 - 1.f) / (e2 + 1.f);
    cst = gf*cst + gi*gg;
    float e2c = __expf(2.f * fminf(fmaxf(cst, -15.f), 15.f));
    const float hval = go * ((e2c - 1.f) / (e2c + 1.f));

    if (l == 63){
      const unsigned unit = ((unsigned)(s + 1) << 16) | f2bf(hval);
      __hip_atomic_store(units + (size_t)s*HDIM + j0, unit,
                         __ATOMIC_RELAXED, __HIP_MEMORY_SCOPE_AGENT);
    }

    if (upf){
      int lok = 1;
      #pragma unroll
      for (int c=0;c<4;++c){
        lok &= (((unsigned)(un[c] >> 16) & 0xffffu) == (unsigned)(s-62));
        lok &= (((unsigned)(un[c] >> 48)) == (unsigned)(s-62));
      }
      if (!__all(lok) && !dead){
        const unsigned long long* bp =
            (const unsigned long long*)(units + (size_t)(s-63)*HDIM) + l;
        int trips = 0, ok;
        do {
          #pragma unroll
          for (int c=0;c<4;++c)
            un[c] = __hip_atomic_load(bp + 64*c, __ATOMIC_RELAXED, __HIP_MEMORY_SCOPE_AGENT);
          int lk = 1;
          #pragma unroll
          for (int c=0;c<4;++c){
            lk &= (((unsigned)(un[c] >> 16) & 0xffffu) == (unsigned)(s-62));
            lk &= (((unsigned)(un[c] >> 48)) == (unsigned)(s-62));
          }
          ok = __all(lk);
        } while (!ok && ++trips < SPIN_LIMIT);
        if (!ok) dead = 1;
      }
      #pragma unroll
      for (int c=0;c<4;++c){
        uvc[2*c]   = bfu((unsigned)un[c] & 0xffffu);
        uvc[2*c+1] = bfu((unsigned)(un[c] >> 32) & 0xffffu);
      }
    } else {
      #pragma unroll
      for (int k=0;k<8;++k) uvc[k] = 0.f;
    }
    if (pf){
      #pragma unroll
      for (int g=0; g<4; ++g)
        pr[g] = psel ? bfu(pw[g] >> 16) : bfu(pw[g] & 0xffffu);
    }
  }
}

// ---------------------------------------------------------------- phase 3
// y[b][t][lab] = sum_j h[s][j] * W_fc[lab][j] + b_fc[lab],  s = t*64 + b
__global__ __launch_bounds__(256) void fc_kernel(
    const unsigned* __restrict__ units,
    const float* __restrict__ Wfc, const float* __restrict__ bfc,
    float* __restrict__ out)
{
  __shared__ float hbuf[8][512];
  const int tid = threadIdx.x;
  const int s0 = blockIdx.x * 8;
  #pragma unroll
  for (int r=0;r<16;++r){
    const int q = tid + 256*r;                 // 0..4095
    const int si = q >> 9, j = q & 511;
    hbuf[si][j] = bfu(units[(size_t)(s0 + si)*HDIM + j] & 0xffffu);
  }
  __syncthreads();
  const int lab = tid & 127, sg = tid >> 7;
  const float* wrow = Wfc + (size_t)lab * HDIM;
  const float bias = bfc[lab];
  for (int si = sg; si < 8; si += 2){
    float sum = 0.f;
    #pragma unroll 4
    for (int j=0;j<HDIM;j+=4){
      const float4 wv = *(const float4*)(wrow + j);
      sum += wv.x*hbuf[si][j] + wv.y*hbuf[si][j+1]
           + wv.z*hbuf[si][j+2] + wv.w*hbuf[si][j+3];
    }
    const int s = s0 + si;
    const int bb = s & 63, tt = s >> 6;
    out[((size_t)(bb*LSEQ + tt))*LAB + lab] = sum + bias;
  }
}

__global__ void sentinel_kernel(float* out, int n){
  const int i = blockIdx.x*256 + threadIdx.x;
  if (i < n) out[i] = 12345.0f;     // diagnostic: ws_size too small
}

extern "C" void kernel_launch(void* const* d_in, const int* in_sizes, int n_in,
                              void* d_out, int out_size, void* d_ws, size_t ws_size,
                              hipStream_t stream)
{
  const float* x   = (const float*)d_in[0];
  const float* hi  = (const float*)d_in[1];
  const float* Wih = (const float*)d_in[2];
  const float* Whh = (const float*)d_in[3];
  const float* bih = (const float*)d_in[4];
  const float* bhh = (const float*)d_in[5];
  const float* Wfc = (const float*)d_in[6];
  const float* bfc = (const float*)d_in[7];
  float* out = (float*)d_out;

  const size_t MB = 1024*1024;
  if (ws_size >= 48*MB + 4096){
    unsigned* pre32 = (unsigned*)d_ws;                               // 32MB
    unsigned* units = (unsigned*)((char*)d_ws + 32*MB);              // 16MB
    unsigned* ctrl  = (unsigned*)((char*)d_ws + 48*MB);              // 4KB
    gemm_pre<<<dim3(64, 16), 256, 0, stream>>>(x, hi, Wih, bih, bhh, pre32);
    lstm_seq3<<<128, 256, 0, stream>>>(Wih, Whh, pre32, units, ctrl);
    lstm_seq<<<128, 256, 0, stream>>>(Wih, Whh, pre32, units, ctrl);
    fc_kernel<<<1024, 256, 0, stream>>>(units, Wfc, bfc, out);
  } else if (ws_size >= 48*MB){
    unsigned* pre32 = (unsigned*)d_ws;                               // 32MB
    unsigned* units = (unsigned*)((char*)d_ws + 32*MB);              // 16MB
    gemm_pre<<<dim3(64, 16), 256, 0, stream>>>(x, hi, Wih, bih, bhh, pre32);
    lstm_seq<<<128, 256, 0, stream>>>(Wih, Whh, pre32, units, nullptr);
    fc_kernel<<<1024, 256, 0, stream>>>(units, Wfc, bfc, out);
  } else {
    sentinel_kernel<<<(out_size + 255)/256, 256, 0, stream>>>(out, out_size);
  }
}

// Round 4
// 15372.792 us; speedup vs baseline: 1.6222x; 1.6222x over previous
//
#include <hip/hip_runtime.h>
#include <stdint.h>

// B=64, L=128, H=512, LAB=128. 8192 strictly-sequential LSTM cell steps
// sharing one (h,c) of size 512:
//   gates[s] = pre[s] + W_p @ h[s-64] + W_hh @ h[s-1]
//   pre[s]   = W_ih[:, :2048] @ [x;hi] + b_ih + b_hh     (parallel GEMM)
//
// ws layout (needs 49MB):
//   [0,32MB)         pre32: bf16-pair-packed u32 [8192][1024]
//   [32,48MB)        units: u32 [8192][512], unit = (tag16<<16)|bf16(h[j]),
//                    tag = step+1 (1..8192); 0xAA poison (tag 0xAAAA) never aliases.
//   [48MB]           ctrl[0]: done counter (poison-relative, +1 per clean WG)
//   [48MB+64KB,+256KB) ring: u32 [128][512], unit format (XCD-local path)
//
// History: R6 XCD-election via s_getreg(XCC_ID) never converged -- signature
// (ranks taken, tags never valid) implies getreg returned the same value for
// all WGs -> "elected" WGs scattered across XCDs -> non-coherent. R7 (coop
// LDS poll, -4x traffic) and R8 (phase-spaced snapshots) both regressed:
// the global-scope step is floored at ~4080cy by MALL visibility+RT, which
// polling schedules cannot remove.
//
// R9: intra-XCD retry WITHOUT getreg. Empty machine + 256-WG grid at
// 1 WG/CU -> CP round-robins blocks across the 8 XCDs, so blocks with
// bid%8==0 co-reside on ONE XCD (32 CUs). Those 32 WGs (8 waves x 512thr,
// 2 outputs/wave) run the recurrence through a 256KB L2-resident ring:
// plain u64 stores + sc0 (L1-bypass, L2-hit) loads => ~300cy RT vs ~1300.
// Tag-guarded: on any failed validation every wave halts WITHOUT
// publishing (units prefix stays bit-identical), done-ctr isn't bumped,
// and the PROVEN global-scope chaser redoes everything. Spin limits cut
// to 4096 trips so a wrong placement assumption costs ~1ms, not 2.8.

#define HDIM   512
#define NSTEP  8192
#define XDIM   2048
#define IN5H   2560
#define LSEQ   128
#define LAB    128
#define SPIN_LIMIT 65536
#define RSPIN  4096
#define TAGMASK 0xFFFF0000FFFF0000ULL

typedef float f32x4 __attribute__((ext_vector_type(4)));
typedef short bf16x8 __attribute__((ext_vector_type(8)));

__device__ __forceinline__ unsigned f2bf(float v){
  unsigned u = __float_as_uint(v);
  u += 0x7fffu + ((u >> 16) & 1u);      // RNE; values bounded (no NaN/Inf)
  return u >> 16;
}
__device__ __forceinline__ float bfu(unsigned half16){   // bf16 bits -> f32
  return __uint_as_float(half16 << 16);
}
template<int CTRL>
__device__ __forceinline__ float dpp_add(float x){
  const int yi = __builtin_amdgcn_update_dpp(0, __float_as_int(x), CTRL, 0xF, 0xF, true);
  return x + __int_as_float(yi);
}
// sum of x across 64 lanes, valid in lane 63 (other lanes partial)
__device__ __forceinline__ float wave_reduce63(float x){
  x = dpp_add<0x111>(x);   // row_shr:1
  x = dpp_add<0x112>(x);   // row_shr:2
  x = dpp_add<0x114>(x);   // row_shr:4
  x = dpp_add<0x118>(x);   // row_shr:8  -> lane15+16k = row sum
  x = dpp_add<0x142>(x);   // row_bcast:15
  x = dpp_add<0x143>(x);   // row_bcast:31 -> lane 63 = total
  return x;
}

// 4x u64 lane-slice of a 2KB row, L1-bypass (L2-visible), blocking.
// Self-contained vmcnt(0) keeps the compiler's counter bookkeeping exact.
__device__ __forceinline__ void ld_row_sc0(const unsigned long long* p,
    unsigned long long& v0, unsigned long long& v1,
    unsigned long long& v2, unsigned long long& v3){
  asm volatile(
      "global_load_dwordx2 %0, %4, off sc0\n\t"
      "global_load_dwordx2 %1, %4, off offset:512 sc0\n\t"
      "global_load_dwordx2 %2, %4, off offset:1024 sc0\n\t"
      "global_load_dwordx2 %3, %4, off offset:1536 sc0\n\t"
      "s_waitcnt vmcnt(0)"
      : "=&v"(v0), "=&v"(v1), "=&v"(v2), "=&v"(v3)
      : "v"(p)
      : "memory");
}

// ---------------------------------------------------------------- phase 1
// pre[s][r] = sum_k xcat[s][k]*W_ih[r][k] + b_ih[r] + b_hh[r], bf16-packed.
__global__ __launch_bounds__(256) void gemm_pre(
    const float* __restrict__ x, const float* __restrict__ hi,
    const float* __restrict__ Wih, const float* __restrict__ bih,
    const float* __restrict__ bhh, unsigned* __restrict__ pre32)
{
  __shared__ unsigned short As[128][40];   // +8 pad, 16B-aligned b128 reads
  __shared__ unsigned short Bs[128][40];
  const int tid = threadIdx.x;
  const int bm = blockIdx.x, bn = blockIdx.y;
  const int lane = tid & 63, wv = tid >> 6;
  const int wm = wv & 1, wn = wv >> 1;

  const int srow = tid >> 1;              // staging row 0..127
  const int ch   = (tid & 1) * 16;        // col half of the 32-wide K chunk

  const int gr = bm*128 + srow;           // global s row
  const int bb = gr & 63, tt = gr >> 6;   // s = t*64 + b
  const float* ax = x  + (size_t)(bb*LSEQ + tt) * 1024;
  const float* ah = hi + (size_t)(bb*LSEQ + tt) * 1024;
  const int R = bn*128 + srow;            // global gate row
  const float* bw = Wih + (size_t)R * IN5H;

  f32x4 acc[4][4];
  #pragma unroll
  for (int m=0;m<4;++m)
    #pragma unroll
    for (int n=0;n<4;++n) acc[m][n] = (f32x4){0.f,0.f,0.f,0.f};

  for (int kc = 0; kc < XDIM; kc += 32){
    const int c0 = kc + ch;
    const float* ap = (c0 < 1024) ? (ax + c0) : (ah + (c0 - 1024));
    #pragma unroll
    for (int q=0;q<4;++q){
      float4 va = *(const float4*)(ap + 4*q);
      float4 vb = *(const float4*)(bw + c0 + 4*q);
      ushort4 ua; ua.x=f2bf(va.x); ua.y=f2bf(va.y); ua.z=f2bf(va.z); ua.w=f2bf(va.w);
      ushort4 ub; ub.x=f2bf(vb.x); ub.y=f2bf(vb.y); ub.z=f2bf(vb.z); ub.w=f2bf(vb.w);
      *(ushort4*)&As[srow][ch + 4*q] = ua;
      *(ushort4*)&Bs[srow][ch + 4*q] = ub;
    }
    __syncthreads();
    bf16x8 afr[4], bfr[4];
    const int mr = wm*64 + (lane & 15);
    const int nr = wn*64 + (lane & 15);
    const int ko = (lane >> 4) * 8;
    #pragma unroll
    for (int m=0;m<4;++m) afr[m] = *(const bf16x8*)&As[mr + 16*m][ko];
    #pragma unroll
    for (int n=0;n<4;++n) bfr[n] = *(const bf16x8*)&Bs[nr + 16*n][ko];
    #pragma unroll
    for (int m=0;m<4;++m)
      #pragma unroll
      for (int n=0;n<4;++n)
        acc[m][n] = __builtin_amdgcn_mfma_f32_16x16x32_bf16(afr[m], bfr[n], acc[m][n], 0, 0, 0);
    __syncthreads();
  }
  // C/D layout: col = lane&15 (N side), row = (lane>>4)*4+q (M side)
  #pragma unroll
  for (int n=0;n<4;++n){
    const int scol = bn*128 + wn*64 + 16*n + (lane & 15);
    const float bias = bih[scol] + bhh[scol];
    #pragma unroll
    for (int m=0;m<4;++m){
      const int sr0 = bm*128 + wm*64 + 16*m + (lane >> 4)*4;
      #pragma unroll
      for (int q=0;q<4;++q){
        const float v = acc[m][n][q] + bias;
        const float vn = __shfl_xor(v, 1, 64);     // neighbor col (scol^1)
        if (!(lane & 1)){
          const unsigned word = f2bf(v) | (f2bf(vn) << 16);
          pre32[(size_t)(sr0 + q) * 1024 + (scol >> 1)] = word;
        }
      }
    }
  }
}

// ---------------------------------------------------------------- phase 2a
// Intra-XCD sequencer. Grid 256 x 512thr (1 WG/CU); participants are
// blocks with bid%8==0 (round-robin dispatch -> all on one XCD; the
// assumption is tag-guarded). rank = bid>>3 (0..31), 8 waves/WG -> wave
// wid = rank*8+wv owns outputs {2wid, 2wid+1}. Lane l holds weight cols
// col(k)=2l+128(k>>1)+(k&1) (u64 words {l,l+64,l+128,l+192} of each row).
// h/u exchanged via the L2-resident ring (plain stores, sc0 loads).
__global__ __launch_bounds__(512, 2)
void lstm_seqx(
    const float* __restrict__ Wih, const float* __restrict__ Whh,
    const unsigned* __restrict__ pre32, unsigned* __restrict__ units,
    unsigned* __restrict__ ring, unsigned* __restrict__ ctrl)
{
  const int bid = blockIdx.x;
  if (bid & 7) return;                   // non-participants exit (placement done)
  const int rank = bid >> 3;             // 0..31
  __shared__ int sh_bad;
  const int tid = threadIdx.x;
  if (tid == 0) sh_bad = 0;
  __syncthreads();

  const int l   = tid & 63;
  const int wv  = tid >> 6;              // 0..7
  const int wid = rank*8 + wv;           // 0..255
  const int j0  = wid*2;                 // outputs j0, j0+1

  // ---- weights into VGPRs (once): col(k) = 2l + 128*(k>>1) + (k&1) ----
  float wH[2][4][8], wU[2][4][8];
  #pragma unroll
  for (int m=0; m<2; ++m)
    #pragma unroll
    for (int g=0; g<4; ++g){
      const float* ph = Whh + (size_t)(g*HDIM + j0 + m)*HDIM;
      const float* pu = Wih + (size_t)(g*HDIM + j0 + m)*IN5H + XDIM;
      #pragma unroll
      for (int k=0; k<8; ++k){
        const int col = 2*l + 128*(k>>1) + (k&1);
        wH[m][g][k] = ph[col]; wU[m][g][k] = pu[col];
      }
    }
  #pragma unroll
  for (int m=0; m<2; ++m)
    #pragma unroll
    for (int g=0; g<4; ++g)
      #pragma unroll
      for (int k=0; k<8; ++k){
        asm volatile("" : "+v"(wH[m][g][k]));
        asm volatile("" : "+v"(wU[m][g][k]));
      }

  // pre word (j0>>1 == wid) holds both outputs: lo=j0, hi=j0+1
  float prA[4], prB[4];
  #pragma unroll
  for (int g=0; g<4; ++g){
    const unsigned w0 = pre32[(size_t)0*1024 + g*256 + wid];
    prA[g] = bfu(w0 & 0xffffu); prB[g] = bfu(w0 >> 16);
  }

  float uvc[8];
  #pragma unroll
  for (int k=0;k<8;++k) uvc[k] = 0.f;

  float c0 = 0.f, c1 = 0.f;
  int halted = 0;

  #pragma clang loop unroll(disable)
  for (int s = 0; s < NSTEP; ++s){
    // ---- prefetch next pre (plain cached; consumed next iteration) ----
    unsigned pw[4];
    const bool pf = (s + 1 < NSTEP);
    if (pf){
      #pragma unroll
      for (int g=0; g<4; ++g)
        pw[g] = pre32[(size_t)(s+1)*1024 + g*256 + wid];
    }

    // ---- poll h[s-1] from ring (intra-XCD L2 round trip) ----
    float hv[8];
    if (s == 0){
      #pragma unroll
      for (int k=0;k<8;++k) hv[k] = 0.f;
    } else {
      const unsigned long long* hp =
          (const unsigned long long*)(ring + (size_t)((s-1) & 127)*HDIM) + l;
      const unsigned long long wq =
          ((unsigned long long)(unsigned)s << 16) |
          ((unsigned long long)(unsigned)s << 48);
      unsigned long long v0,v1,v2,v3;
      int trips = 0, ok;
      do {
        ld_row_sc0(hp, v0, v1, v2, v3);
        const int lok =
            (((v0^wq)|(v1^wq)|(v2^wq)|(v3^wq)) & TAGMASK) == 0;
        ok = __all(lok);
      } while (!ok && ++trips < RSPIN);
      if (!ok){ halted = 1; sh_bad = 1; break; }   // halt WITHOUT publishing
      hv[0] = bfu((unsigned)v0 & 0xffffu);
      hv[1] = bfu((unsigned)(v0 >> 32) & 0xffffu);
      hv[2] = bfu((unsigned)v1 & 0xffffu);
      hv[3] = bfu((unsigned)(v1 >> 32) & 0xffffu);
      hv[4] = bfu((unsigned)v2 & 0xffffu);
      hv[5] = bfu((unsigned)(v2 >> 32) & 0xffffu);
      hv[6] = bfu((unsigned)v3 & 0xffffu);
      hv[7] = bfu((unsigned)(v3 >> 32) & 0xffffu);
    }

    // ---- matvec: 8 gate rows (2 outputs x 4 gates), h + u parts ----
    float a00=0.f,a01=0.f,a02=0.f,a03=0.f;   // output j0
    float a10=0.f,a11=0.f,a12=0.f,a13=0.f;   // output j0+1
    #pragma unroll
    for (int k=0;k<8;++k){
      a00 += wH[0][0][k]*hv[k]; a01 += wH[0][1][k]*hv[k];
      a02 += wH[0][2][k]*hv[k]; a03 += wH[0][3][k]*hv[k];
      a10 += wH[1][0][k]*hv[k]; a11 += wH[1][1][k]*hv[k];
      a12 += wH[1][2][k]*hv[k]; a13 += wH[1][3][k]*hv[k];
    }
    #pragma unroll
    for (int k=0;k<8;++k){
      a00 += wU[0][0][k]*uvc[k]; a01 += wU[0][1][k]*uvc[k];
      a02 += wU[0][2][k]*uvc[k]; a03 += wU[0][3][k]*uvc[k];
      a10 += wU[1][0][k]*uvc[k]; a11 += wU[1][1][k]*uvc[k];
      a12 += wU[1][2][k]*uvc[k]; a13 += wU[1][3][k]*uvc[k];
    }
    a00 = wave_reduce63(a00); a01 = wave_reduce63(a01);
    a02 = wave_reduce63(a02); a03 = wave_reduce63(a03);
    a10 = wave_reduce63(a10); a11 = wave_reduce63(a11);
    a12 = wave_reduce63(a12); a13 = wave_reduce63(a13);

    // ---- pointwise, both outputs (lane 63's chain valid) ----
    const unsigned tag = (unsigned)(s + 1) << 16;
    float gi = a00 + prA[0], gf = a01 + prA[1];
    float gg = a02 + prA[2], go = a03 + prA[3];
    gi = 1.f/(1.f + __expf(-gi));
    gf = 1.f/(1.f + __expf(-gf));
    go = 1.f/(1.f + __expf(-go));
    float e2 = __expf(2.f * fminf(fmaxf(gg, -15.f), 15.f));
    gg = (e2 - 1.f) / (e2 + 1.f);
    c0 = gf*c0 + gi*gg;
    float e2c = __expf(2.f * fminf(fmaxf(c0, -15.f), 15.f));
    const unsigned unit0 = tag | f2bf(go * ((e2c - 1.f)/(e2c + 1.f)));

    gi = a10 + prB[0]; gf = a11 + prB[1];
    gg = a12 + prB[2]; go = a13 + prB[3];
    gi = 1.f/(1.f + __expf(-gi));
    gf = 1.f/(1.f + __expf(-gf));
    go = 1.f/(1.f + __expf(-go));
    e2 = __expf(2.f * fminf(fmaxf(gg, -15.f), 15.f));
    gg = (e2 - 1.f) / (e2 + 1.f);
    c1 = gf*c1 + gi*gg;
    e2c = __expf(2.f * fminf(fmaxf(c1, -15.f), 15.f));
    const unsigned unit1 = tag | f2bf(go * ((e2c - 1.f)/(e2c + 1.f)));

    if (l == 63){
      const unsigned long long pk =
          (unsigned long long)unit0 | ((unsigned long long)unit1 << 32);
      *(volatile unsigned long long*)
          (ring + (size_t)(s & 127)*HDIM + j0) = pk;          // L2 (drives loop)
      __builtin_nontemporal_store(pk,
          (unsigned long long*)(units + (size_t)s*HDIM + j0)); // output copy
    }

    // ---- u for step s+1: ring row (s+1)-64, tag s-62 (63-step slack;
    //      blocking sc0 load overlaps our own publish's propagation) ----
    if (pf && s + 1 >= 64){
      const unsigned long long* up =
          (const unsigned long long*)(ring + (size_t)((s-63) & 127)*HDIM) + l;
      const unsigned long long uq =
          ((unsigned long long)(unsigned)(s-62) << 16) |
          ((unsigned long long)(unsigned)(s-62) << 48);
      unsigned long long u0,u1,u2,u3;
      int trips = 0, ok;
      do {
        ld_row_sc0(up, u0, u1, u2, u3);
        const int lok =
            (((u0^uq)|(u1^uq)|(u2^uq)|(u3^uq)) & TAGMASK) == 0;
        ok = __all(lok);
      } while (!ok && ++trips < RSPIN);
      if (!ok){ halted = 1; sh_bad = 1; break; }
      uvc[0] = bfu((unsigned)u0 & 0xffffu);
      uvc[1] = bfu((unsigned)(u0 >> 32) & 0xffffu);
      uvc[2] = bfu((unsigned)u1 & 0xffffu);
      uvc[3] = bfu((unsigned)(u1 >> 32) & 0xffffu);
      uvc[4] = bfu((unsigned)u2 & 0xffffu);
      uvc[5] = bfu((unsigned)(u2 >> 32) & 0xffffu);
      uvc[6] = bfu((unsigned)u3 & 0xffffu);
      uvc[7] = bfu((unsigned)(u3 >> 32) & 0xffffu);
    } else {
      #pragma unroll
      for (int k=0;k<8;++k) uvc[k] = 0.f;
    }
    if (pf){
      #pragma unroll
      for (int g=0; g<4; ++g){
        prA[g] = bfu(pw[g] & 0xffffu); prB[g] = bfu(pw[g] >> 16);
      }
    }
  }

  __syncthreads();
  if (tid == 0 && sh_bad == 0) atomicAdd(ctrl, 1u);   // per-WG completion
  (void)halted;
}

// ---------------------------------------------------------------- phase 2b
// Global-scope proven path (chaser / legacy). Unchanged math; early-exits
// when lstm_seqx attests full completion (done == poison + 32 WGs).
__global__ __launch_bounds__(256)
__attribute__((amdgpu_waves_per_eu(1,1)))
void lstm_seq(
    const float* __restrict__ Wih, const float* __restrict__ Whh,
    const unsigned* __restrict__ pre32, unsigned* __restrict__ units,
    const unsigned* __restrict__ done_ctrl)
{
  if (done_ctrl){
    if (*(volatile const unsigned*)done_ctrl == 0xAAAAAAAAu + 32u) return;
  }
  const int tid = threadIdx.x;
  const int l = tid & 63;
  const int j0 = blockIdx.x * 4 + (tid >> 6);      // 0..511

  // ---- weights into VGPRs (once): col(k) = 2l + 128*(k>>1) + (k&1) ----
  float wh[4][8], wu[4][8];
  #pragma unroll
  for (int g=0; g<4; ++g){
    const float* ph = Whh + (size_t)(g*HDIM + j0)*HDIM;
    const float* pu = Wih + (size_t)(g*HDIM + j0)*IN5H + XDIM;
    #pragma unroll
    for (int k=0; k<8; ++k){
      const int col = 2*l + 128*(k>>1) + (k&1);
      wh[g][k] = ph[col]; wu[g][k] = pu[col];
    }
  }
  #pragma unroll
  for (int g=0; g<4; ++g)
    #pragma unroll
    for (int k=0; k<8; ++k){
      asm volatile("" : "+v"(wh[g][k]));
      asm volatile("" : "+v"(wu[g][k]));
    }

  const int phalf = j0 >> 1, psel = j0 & 1;
  float pr[4];
  #pragma unroll
  for (int g=0; g<4; ++g){
    const unsigned w0 = pre32[(size_t)0*1024 + g*256 + phalf];
    pr[g] = psel ? bfu(w0 >> 16) : bfu(w0 & 0xffffu);
  }

  float uvc[8];
  #pragma unroll
  for (int k=0;k<8;++k) uvc[k] = 0.f;

  float cst = 0.f;
  int dead = 0;

  for (int s = 0; s < NSTEP; ++s){
    unsigned pw[4];
    const bool pf  = (s + 1 < NSTEP);
    const bool upf = (s + 1 >= 64) && pf;
    if (pf){
      #pragma unroll
      for (int g=0; g<4; ++g)
        pw[g] = pre32[(size_t)(s+1)*1024 + g*256 + phalf];
    }
    unsigned long long un[4];
    if (upf){
      const unsigned long long* bp =
          (const unsigned long long*)(units + (size_t)(s-63)*HDIM) + l;
      #pragma unroll
      for (int c=0;c<4;++c)
        un[c] = __hip_atomic_load(bp + 64*c, __ATOMIC_RELAXED, __HIP_MEMORY_SCOPE_AGENT);
    }

    float hv[8];
    if (s == 0){
      #pragma unroll
      for (int k=0;k<8;++k) hv[k] = 0.f;
    } else {
      const unsigned long long* bp =
          (const unsigned long long*)(units + (size_t)(s-1)*HDIM) + l;
      unsigned long long v[4];
      if (dead){
        #pragma unroll
        for (int c=0;c<4;++c) v[c] = __hip_atomic_load(bp + 64*c, __ATOMIC_RELAXED, __HIP_MEMORY_SCOPE_AGENT);
      } else {
        int trips = 0, ok;
        do {
          #pragma unroll
          for (int c=0;c<4;++c) v[c] = __hip_atomic_load(bp + 64*c, __ATOMIC_RELAXED, __HIP_MEMORY_SCOPE_AGENT);
          int lok = 1;
          #pragma unroll
          for (int c=0;c<4;++c){
            lok &= (((unsigned)(v[c] >> 16) & 0xffffu) == (unsigned)s);
            lok &= (((unsigned)(v[c] >> 48)) == (unsigned)s);
          }
          ok = __all(lok);
        } while (!ok && ++trips < SPIN_LIMIT);
        if (!ok) dead = 1;
      }
      #pragma unroll
      for (int c=0;c<4;++c){
        hv[2*c]   = bfu((unsigned)v[c] & 0xffffu);
        hv[2*c+1] = bfu((unsigned)(v[c] >> 32) & 0xffffu);
      }
    }

    float a0=0.f, a1=0.f, a2=0.f, a3=0.f;
    #pragma unroll
    for (int k=0;k<8;++k){
      a0 += wh[0][k]*hv[k]; a1 += wh[1][k]*hv[k];
      a2 += wh[2][k]*hv[k]; a3 += wh[3][k]*hv[k];
    }
    #pragma unroll
    for (int k=0;k<8;++k){
      a0 += wu[0][k]*uvc[k]; a1 += wu[1][k]*uvc[k];
      a2 += wu[2][k]*uvc[k]; a3 += wu[3][k]*uvc[k];
    }
    a0 = wave_reduce63(a0);
    a1 = wave_reduce63(a1);
    a2 = wave_reduce63(a2);
    a3 = wave_reduce63(a3);

    float gi = a0 + pr[0];
    float gf = a1 + pr[1];
    float gg = a2 + pr[2];
    float go = a3 + pr[3];
    gi = 1.f/(1.f + __expf(-gi));
    gf = 1.f/(1.f + __expf(-gf));
    go = 1.f/(1.f + __expf(-go));
    float e2 = __expf(2.f * fminf(fmaxf(gg, -15.f), 15.f));
    gg = (e2 - 1.f) / (e2 + 1.f);
    cst = gf*cst + gi*gg;
    float e2c = __expf(2.f * fminf(fmaxf(cst, -15.f), 15.f));
    const float hval = go * ((e2c - 1.f) / (e2c + 1.f));

    if (l == 63){
      const unsigned unit = ((unsigned)(s + 1) << 16) | f2bf(hval);
      __hip_atomic_store(units + (size_t)s*HDIM + j0, unit,
                         __ATOMIC_RELAXED, __HIP_MEMORY_SCOPE_AGENT);
    }

    if (upf){
      int lok = 1;
      #pragma unroll
      for (int c=0;c<4;++c){
        lok &= (((unsigned)(un[c] >> 16) & 0xffffu) == (unsigned)(s-62));
        lok &= (((unsigned)(un[c] >> 48)) == (unsigned)(s-62));
      }
      if (!__all(lok) && !dead){
        const unsigned long long* bp =
            (const unsigned long long*)(units + (size_t)(s-63)*HDIM) + l;
        int trips = 0, ok;
        do {
          #pragma unroll
          for (int c=0;c<4;++c)
            un[c] = __hip_atomic_load(bp + 64*c, __ATOMIC_RELAXED, __HIP_MEMORY_SCOPE_AGENT);
          int lk = 1;
          #pragma unroll
          for (int c=0;c<4;++c){
            lk &= (((unsigned)(un[c] >> 16) & 0xffffu) == (unsigned)(s-62));
            lk &= (((unsigned)(un[c] >> 48)) == (unsigned)(s-62));
          }
          ok = __all(lk);
        } while (!ok && ++trips < SPIN_LIMIT);
        if (!ok) dead = 1;
      }
      #pragma unroll
      for (int c=0;c<4;++c){
        uvc[2*c]   = bfu((unsigned)un[c] & 0xffffu);
        uvc[2*c+1] = bfu((unsigned)(un[c] >> 32) & 0xffffu);
      }
    } else {
      #pragma unroll
      for (int k=0;k<8;++k) uvc[k] = 0.f;
    }
    if (pf){
      #pragma unroll
      for (int g=0; g<4; ++g)
        pr[g] = psel ? bfu(pw[g] >> 16) : bfu(pw[g] & 0xffffu);
    }
  }
}

// ---------------------------------------------------------------- phase 3
// y[b][t][lab] = sum_j h[s][j] * W_fc[lab][j] + b_fc[lab],  s = t*64 + b
__global__ __launch_bounds__(256) void fc_kernel(
    const unsigned* __restrict__ units,
    const float* __restrict__ Wfc, const float* __restrict__ bfc,
    float* __restrict__ out)
{
  __shared__ float hbuf[8][512];
  const int tid = threadIdx.x;
  const int s0 = blockIdx.x * 8;
  #pragma unroll
  for (int r=0;r<16;++r){
    const int q = tid + 256*r;                 // 0..4095
    const int si = q >> 9, j = q & 511;
    hbuf[si][j] = bfu(units[(size_t)(s0 + si)*HDIM + j] & 0xffffu);
  }
  __syncthreads();
  const int lab = tid & 127, sg = tid >> 7;
  const float* wrow = Wfc + (size_t)lab * HDIM;
  const float bias = bfc[lab];
  for (int si = sg; si < 8; si += 2){
    float sum = 0.f;
    #pragma unroll 4
    for (int j=0;j<HDIM;j+=4){
      const float4 wv = *(const float4*)(wrow + j);
      sum += wv.x*hbuf[si][j] + wv.y*hbuf[si][j+1]
           + wv.z*hbuf[si][j+2] + wv.w*hbuf[si][j+3];
    }
    const int s = s0 + si;
    const int bb = s & 63, tt = s >> 6;
    out[((size_t)(bb*LSEQ + tt))*LAB + lab] = sum + bias;
  }
}

__global__ void sentinel_kernel(float* out, int n){
  const int i = blockIdx.x*256 + threadIdx.x;
  if (i < n) out[i] = 12345.0f;     // diagnostic: ws_size too small
}

extern "C" void kernel_launch(void* const* d_in, const int* in_sizes, int n_in,
                              void* d_out, int out_size, void* d_ws, size_t ws_size,
                              hipStream_t stream)
{
  const float* x   = (const float*)d_in[0];
  const float* hi  = (const float*)d_in[1];
  const float* Wih = (const float*)d_in[2];
  const float* Whh = (const float*)d_in[3];
  const float* bih = (const float*)d_in[4];
  const float* bhh = (const float*)d_in[5];
  const float* Wfc = (const float*)d_in[6];
  const float* bfc = (const float*)d_in[7];
  float* out = (float*)d_out;

  const size_t MB = 1024*1024;
  if (ws_size >= 49*MB){
    unsigned* pre32 = (unsigned*)d_ws;                               // 32MB
    unsigned* units = (unsigned*)((char*)d_ws + 32*MB);              // 16MB
    unsigned* ctrl  = (unsigned*)((char*)d_ws + 48*MB);              // done ctr
    unsigned* ring  = (unsigned*)((char*)d_ws + 48*MB + 64*1024);    // 256KB
    gemm_pre<<<dim3(64, 16), 256, 0, stream>>>(x, hi, Wih, bih, bhh, pre32);
    lstm_seqx<<<256, 512, 0, stream>>>(Wih, Whh, pre32, units, ring, ctrl);
    lstm_seq<<<128, 256, 0, stream>>>(Wih, Whh, pre32, units, ctrl);
    fc_kernel<<<1024, 256, 0, stream>>>(units, Wfc, bfc, out);
  } else if (ws_size >= 48*MB){
    unsigned* pre32 = (unsigned*)d_ws;                               // 32MB
    unsigned* units = (unsigned*)((char*)d_ws + 32*MB);              // 16MB
    gemm_pre<<<dim3(64, 16), 256, 0, stream>>>(x, hi, Wih, bih, bhh, pre32);
    lstm_seq<<<128, 256, 0, stream>>>(Wih, Whh, pre32, units, nullptr);
    fc_kernel<<<1024, 256, 0, stream>>>(units, Wfc, bfc, out);
  } else {
    sentinel_kernel<<<(out_size + 255)/256, 256, 0, stream>>>(out, out_size);
  }
}

// Round 6
// 14508.539 us; speedup vs baseline: 1.7189x; 1.0596x over previous
//
#include <hip/hip_runtime.h>
#include <stdint.h>

// B=64, L=128, H=512, LAB=128. 8192 strictly-sequential LSTM cell steps
// sharing one (h,c) of size 512:
//   gates[s] = pre[s] + W_p @ h[s-64] + W_hh @ h[s-1]
//   pre[s]   = W_ih[:, :2048] @ [x;hi] + b_ih + b_hh     (parallel GEMM)
//
// ws layout (needs 48MB):
//   [0,32MB)  pre32: bf16-pair-packed u32 [8192][1024]  ([s][g*256 + j>>1])
//   [32,48MB) units: u32 [8192][512], unit = (tag16 << 16) | bf16(h[j])
//             tag = step+1 (1..8192); 0xAA poison tag 0xAAAA never aliases.
//
// R11 (final): REVERT to the proven R0 kernel. Session ledger: R6/R9
// (XCD-local rings; placement+coherence unverifiable from HIP) never
// converged; R7 (cooperative LDS poll, 4x less poll traffic) -52%; R8
// (phase-spaced snapshots via compiler loads) -75% (compiler serializes
// all batches behind vmcnt(0)); R10 (counted-vmcnt inline-asm load engine)
// FAILED correctness (regalloc live-range copies of in-flight asm load
// destinations -> tag-valid/value-wrong publishes that poison the chaser).
// The workload is a latency-bound serial recurrence: 8192 dependent
// agent-scope (MALL) round trips at ~1.70us each; HBM 0.3%, VALU 12.5%,
// MfmaUtil 0. No software lever tested on this platform shortens the hop.
//
// lstm_seq: 512 waves (128 WG x 256 thr), wave j0 owns h-lane j0.
//  - amdgpu_waves_per_eu(1,1): occupancy is structurally 1 wave/EU (128 WGs
//    on 256 CUs), so tell the allocator -> weights stay in VGPRs.
//  - poll = 4 x u64 relaxed agent atomic loads (each 4B half self-tagged).
//  - reduce via DPP (row_shr 1/2/4/8 + row_bcast 15/31) -> lane 63.
//  - all step-s+1 loads (u = h[s-63], pre[s+1]) issued BEFORE the h[s-1]
//    spin: one round-trip latency per step.

#define HDIM   512
#define NSTEP  8192
#define XDIM   2048
#define IN5H   2560
#define LSEQ   128
#define LAB    128
#define SPIN_LIMIT 65536

typedef float f32x4 __attribute__((ext_vector_type(4)));
typedef short bf16x8 __attribute__((ext_vector_type(8)));

__device__ __forceinline__ unsigned f2bf(float v){
  unsigned u = __float_as_uint(v);
  u += 0x7fffu + ((u >> 16) & 1u);      // RNE; values bounded (no NaN/Inf)
  return u >> 16;
}
__device__ __forceinline__ float bfu(unsigned half16){   // bf16 bits -> f32
  return __uint_as_float(half16 << 16);
}
template<int CTRL>
__device__ __forceinline__ float dpp_add(float x){
  const int yi = __builtin_amdgcn_update_dpp(0, __float_as_int(x), CTRL, 0xF, 0xF, true);
  return x + __int_as_float(yi);
}
// sum of x across 64 lanes, valid in lane 63 (other lanes partial)
__device__ __forceinline__ float wave_reduce63(float x){
  x = dpp_add<0x111>(x);   // row_shr:1
  x = dpp_add<0x112>(x);   // row_shr:2
  x = dpp_add<0x114>(x);   // row_shr:4
  x = dpp_add<0x118>(x);   // row_shr:8  -> lane15+16k = row sum
  x = dpp_add<0x142>(x);   // row_bcast:15
  x = dpp_add<0x143>(x);   // row_bcast:31 -> lane 63 = total
  return x;
}

// ---------------------------------------------------------------- phase 1
// pre[s][r] = sum_k xcat[s][k]*W_ih[r][k] + b_ih[r] + b_hh[r], bf16-packed.
__global__ __launch_bounds__(256) void gemm_pre(
    const float* __restrict__ x, const float* __restrict__ hi,
    const float* __restrict__ Wih, const float* __restrict__ bih,
    const float* __restrict__ bhh, unsigned* __restrict__ pre32)
{
  __shared__ unsigned short As[128][40];   // +8 pad, 16B-aligned b128 reads
  __shared__ unsigned short Bs[128][40];
  const int tid = threadIdx.x;
  const int bm = blockIdx.x, bn = blockIdx.y;
  const int lane = tid & 63, wv = tid >> 6;
  const int wm = wv & 1, wn = wv >> 1;

  const int srow = tid >> 1;              // staging row 0..127
  const int ch   = (tid & 1) * 16;        // col half of the 32-wide K chunk

  const int gr = bm*128 + srow;           // global s row
  const int bb = gr & 63, tt = gr >> 6;   // s = t*64 + b
  const float* ax = x  + (size_t)(bb*LSEQ + tt) * 1024;
  const float* ah = hi + (size_t)(bb*LSEQ + tt) * 1024;
  const int R = bn*128 + srow;            // global gate row
  const float* bw = Wih + (size_t)R * IN5H;

  f32x4 acc[4][4];
  #pragma unroll
  for (int m=0;m<4;++m)
    #pragma unroll
    for (int n=0;n<4;++n) acc[m][n] = (f32x4){0.f,0.f,0.f,0.f};

  for (int kc = 0; kc < XDIM; kc += 32){
    const int c0 = kc + ch;
    const float* ap = (c0 < 1024) ? (ax + c0) : (ah + (c0 - 1024));
    #pragma unroll
    for (int q=0;q<4;++q){
      float4 va = *(const float4*)(ap + 4*q);
      float4 vb = *(const float4*)(bw + c0 + 4*q);
      ushort4 ua; ua.x=f2bf(va.x); ua.y=f2bf(va.y); ua.z=f2bf(va.z); ua.w=f2bf(va.w);
      ushort4 ub; ub.x=f2bf(vb.x); ub.y=f2bf(vb.y); ub.z=f2bf(vb.z); ub.w=f2bf(vb.w);
      *(ushort4*)&As[srow][ch + 4*q] = ua;
      *(ushort4*)&Bs[srow][ch + 4*q] = ub;
    }
    __syncthreads();
    bf16x8 afr[4], bfr[4];
    const int mr = wm*64 + (lane & 15);
    const int nr = wn*64 + (lane & 15);
    const int ko = (lane >> 4) * 8;
    #pragma unroll
    for (int m=0;m<4;++m) afr[m] = *(const bf16x8*)&As[mr + 16*m][ko];
    #pragma unroll
    for (int n=0;n<4;++n) bfr[n] = *(const bf16x8*)&Bs[nr + 16*n][ko];
    #pragma unroll
    for (int m=0;m<4;++m)
      #pragma unroll
      for (int n=0;n<4;++n)
        acc[m][n] = __builtin_amdgcn_mfma_f32_16x16x32_bf16(afr[m], bfr[n], acc[m][n], 0, 0, 0);
    __syncthreads();
  }
  // C/D layout: col = lane&15 (N side), row = (lane>>4)*4+q (M side)
  #pragma unroll
  for (int n=0;n<4;++n){
    const int scol = bn*128 + wn*64 + 16*n + (lane & 15);
    const float bias = bih[scol] + bhh[scol];
    #pragma unroll
    for (int m=0;m<4;++m){
      const int sr0 = bm*128 + wm*64 + 16*m + (lane >> 4)*4;
      #pragma unroll
      for (int q=0;q<4;++q){
        const float v = acc[m][n][q] + bias;
        const float vn = __shfl_xor(v, 1, 64);     // neighbor col (scol^1)
        if (!(lane & 1)){
          const unsigned word = f2bf(v) | (f2bf(vn) << 16);
          pre32[(size_t)(sr0 + q) * 1024 + (scol >> 1)] = word;
        }
      }
    }
  }
}

// ---------------------------------------------------------------- phase 2
// 512 independent waves; wave j0 owns h-lane j0 (gate rows {g*512+j0}).
// Lane l holds weight cols {2l+128c, 2l+128c+1 : c=0..3} (u64-load layout).
__global__ __launch_bounds__(256)
__attribute__((amdgpu_waves_per_eu(1,1)))
void lstm_seq(
    const float* __restrict__ Wih, const float* __restrict__ Whh,
    const unsigned* __restrict__ pre32, unsigned* __restrict__ units)
{
  const int tid = threadIdx.x;
  const int l = tid & 63;
  const int j0 = blockIdx.x * 4 + (tid >> 6);      // 0..511

  // ---- weights into VGPRs (once): col(k) = 2l + 128*(k>>1) + (k&1) ----
  float wh[4][8], wu[4][8];
  #pragma unroll
  for (int g=0; g<4; ++g){
    const float* ph = Whh + (size_t)(g*HDIM + j0)*HDIM;
    const float* pu = Wih + (size_t)(g*HDIM + j0)*IN5H + XDIM;
    #pragma unroll
    for (int k=0; k<8; ++k){
      const int col = 2*l + 128*(k>>1) + (k&1);
      wh[g][k] = ph[col]; wu[g][k] = pu[col];
    }
  }
  // Pin: opaque asm def blocks rematerialization/sinking of the loads.
  #pragma unroll
  for (int g=0; g<4; ++g)
    #pragma unroll
    for (int k=0; k<8; ++k){
      asm volatile("" : "+v"(wh[g][k]));
      asm volatile("" : "+v"(wu[g][k]));
    }

  const int phalf = j0 >> 1, psel = j0 & 1;
  float pr[4];
  #pragma unroll
  for (int g=0; g<4; ++g){
    const unsigned w0 = pre32[(size_t)0*1024 + g*256 + phalf];
    pr[g] = psel ? bfu(w0 >> 16) : bfu(w0 & 0xffffu);
  }

  float uvc[8];                       // u for current step (decoded)
  #pragma unroll
  for (int k=0;k<8;++k) uvc[k] = 0.f;

  float cst = 0.f;
  int dead = 0;

  for (int s = 0; s < NSTEP; ++s){
    // ---- issue ALL next-step loads first (share the poll's RT window) ----
    unsigned pw[4];
    const bool pf  = (s + 1 < NSTEP);
    const bool upf = (s + 1 >= 64) && pf;
    if (pf){
      #pragma unroll
      for (int g=0; g<4; ++g)
        pw[g] = pre32[(size_t)(s+1)*1024 + g*256 + phalf];   // plain, cached
    }
    unsigned long long un[4];
    if (upf){
      const unsigned long long* bp =
          (const unsigned long long*)(units + (size_t)(s-63)*HDIM) + l;
      #pragma unroll
      for (int c=0;c<4;++c)
        un[c] = __hip_atomic_load(bp + 64*c, __ATOMIC_RELAXED, __HIP_MEMORY_SCOPE_AGENT);
    }

    // ---- poll h[s-1] (both 4B halves tagged s) ----
    float hv[8];
    if (s == 0){
      #pragma unroll
      for (int k=0;k<8;++k) hv[k] = 0.f;
    } else {
      const unsigned long long* bp =
          (const unsigned long long*)(units + (size_t)(s-1)*HDIM) + l;
      unsigned long long v[4];
      if (dead){
        #pragma unroll
        for (int c=0;c<4;++c) v[c] = __hip_atomic_load(bp + 64*c, __ATOMIC_RELAXED, __HIP_MEMORY_SCOPE_AGENT);
      } else {
        int trips = 0, ok;
        do {
          #pragma unroll
          for (int c=0;c<4;++c) v[c] = __hip_atomic_load(bp + 64*c, __ATOMIC_RELAXED, __HIP_MEMORY_SCOPE_AGENT);
          int lok = 1;
          #pragma unroll
          for (int c=0;c<4;++c){
            lok &= (((unsigned)(v[c] >> 16) & 0xffffu) == (unsigned)s);
            lok &= (((unsigned)(v[c] >> 48)) == (unsigned)s);
          }
          ok = __all(lok);
        } while (!ok && ++trips < SPIN_LIMIT);
        if (!ok) dead = 1;
      }
      #pragma unroll
      for (int c=0;c<4;++c){
        hv[2*c]   = bfu((unsigned)v[c] & 0xffffu);
        hv[2*c+1] = bfu((unsigned)(v[c] >> 32) & 0xffffu);
      }
    }

    // ---- matvec: 4 gate rows x (8 h-cols + 8 u-cols) ----
    float a0=0.f, a1=0.f, a2=0.f, a3=0.f;
    #pragma unroll
    for (int k=0;k<8;++k){
      a0 += wh[0][k]*hv[k]; a1 += wh[1][k]*hv[k];
      a2 += wh[2][k]*hv[k]; a3 += wh[3][k]*hv[k];
    }
    #pragma unroll
    for (int k=0;k<8;++k){
      a0 += wu[0][k]*uvc[k]; a1 += wu[1][k]*uvc[k];
      a2 += wu[2][k]*uvc[k]; a3 += wu[3][k]*uvc[k];
    }
    a0 = wave_reduce63(a0);
    a1 = wave_reduce63(a1);
    a2 = wave_reduce63(a2);
    a3 = wave_reduce63(a3);

    // ---- pointwise (only lane 63's chain is valid; only it publishes) ----
    float gi = a0 + pr[0];
    float gf = a1 + pr[1];
    float gg = a2 + pr[2];
    float go = a3 + pr[3];
    gi = 1.f/(1.f + __expf(-gi));
    gf = 1.f/(1.f + __expf(-gf));
    go = 1.f/(1.f + __expf(-go));
    float e2 = __expf(2.f * fminf(fmaxf(gg, -15.f), 15.f));
    gg = (e2 - 1.f) / (e2 + 1.f);
    cst = gf*cst + gi*gg;
    float e2c = __expf(2.f * fminf(fmaxf(cst, -15.f), 15.f));
    const float hval = go * ((e2c - 1.f) / (e2c + 1.f));

    if (l == 63){
      const unsigned unit = ((unsigned)(s + 1) << 16) | f2bf(hval);
      __hip_atomic_store(units + (size_t)s*HDIM + j0, unit,
                         __ATOMIC_RELAXED, __HIP_MEMORY_SCOPE_AGENT);
    }

    // ---- finalize prefetches (off critical path) ----
    if (upf){
      int lok = 1;
      #pragma unroll
      for (int c=0;c<4;++c){
        lok &= (((unsigned)(un[c] >> 16) & 0xffffu) == (unsigned)(s-62));
        lok &= (((unsigned)(un[c] >> 48)) == (unsigned)(s-62));
      }
      if (!__all(lok) && !dead){
        // should never happen (62-step slack); bounded fallback spin
        const unsigned long long* bp =
            (const unsigned long long*)(units + (size_t)(s-63)*HDIM) + l;
        int trips = 0, ok;
        do {
          #pragma unroll
          for (int c=0;c<4;++c)
            un[c] = __hip_atomic_load(bp + 64*c, __ATOMIC_RELAXED, __HIP_MEMORY_SCOPE_AGENT);
          int lk = 1;
          #pragma unroll
          for (int c=0;c<4;++c){
            lk &= (((unsigned)(un[c] >> 16) & 0xffffu) == (unsigned)(s-62));
            lk &= (((unsigned)(un[c] >> 48)) == (unsigned)(s-62));
          }
          ok = __all(lk);
        } while (!ok && ++trips < SPIN_LIMIT);
        if (!ok) dead = 1;
      }
      #pragma unroll
      for (int c=0;c<4;++c){
        uvc[2*c]   = bfu((unsigned)un[c] & 0xffffu);
        uvc[2*c+1] = bfu((unsigned)(un[c] >> 32) & 0xffffu);
      }
    } else {
      #pragma unroll
      for (int k=0;k<8;++k) uvc[k] = 0.f;
    }
    if (pf){
      #pragma unroll
      for (int g=0; g<4; ++g)
        pr[g] = psel ? bfu(pw[g] >> 16) : bfu(pw[g] & 0xffffu);
    }
  }
}

// ---------------------------------------------------------------- phase 3
// y[b][t][lab] = sum_j h[s][j] * W_fc[lab][j] + b_fc[lab],  s = t*64 + b
__global__ __launch_bounds__(256) void fc_kernel(
    const unsigned* __restrict__ units,
    const float* __restrict__ Wfc, const float* __restrict__ bfc,
    float* __restrict__ out)
{
  __shared__ float hbuf[8][512];
  const int tid = threadIdx.x;
  const int s0 = blockIdx.x * 8;
  #pragma unroll
  for (int r=0;r<16;++r){
    const int q = tid + 256*r;                 // 0..4095
    const int si = q >> 9, j = q & 511;
    hbuf[si][j] = bfu(units[(size_t)(s0 + si)*HDIM + j] & 0xffffu);
  }
  __syncthreads();
  const int lab = tid & 127, sg = tid >> 7;
  const float* wrow = Wfc + (size_t)lab * HDIM;
  const float bias = bfc[lab];
  for (int si = sg; si < 8; si += 2){
    float sum = 0.f;
    #pragma unroll 4
    for (int j=0;j<HDIM;j+=4){
      const float4 wv = *(const float4*)(wrow + j);
      sum += wv.x*hbuf[si][j] + wv.y*hbuf[si][j+1]
           + wv.z*hbuf[si][j+2] + wv.w*hbuf[si][j+3];
    }
    const int s = s0 + si;
    const int bb = s & 63, tt = s >> 6;
    out[((size_t)(bb*LSEQ + tt))*LAB + lab] = sum + bias;
  }
}

__global__ void sentinel_kernel(float* out, int n){
  const int i = blockIdx.x*256 + threadIdx.x;
  if (i < n) out[i] = 12345.0f;     // diagnostic: ws_size too small
}

extern "C" void kernel_launch(void* const* d_in, const int* in_sizes, int n_in,
                              void* d_out, int out_size, void* d_ws, size_t ws_size,
                              hipStream_t stream)
{
  const float* x   = (const float*)d_in[0];
  const float* hi  = (const float*)d_in[1];
  const float* Wih = (const float*)d_in[2];
  const float* Whh = (const float*)d_in[3];
  const float* bih = (const float*)d_in[4];
  const float* bhh = (const float*)d_in[5];
  const float* Wfc = (const float*)d_in[6];
  const float* bfc = (const float*)d_in[7];
  float* out = (float*)d_out;

  const size_t MB = 1024*1024;
  if (ws_size >= 48*MB){
    unsigned* pre32 = (unsigned*)d_ws;                          // 32MB
    unsigned* units = (unsigned*)((char*)d_ws + 32*MB);         // 16MB
    gemm_pre<<<dim3(64, 16), 256, 0, stream>>>(x, hi, Wih, bih, bhh, pre32);
    lstm_seq<<<128, 256, 0, stream>>>(Wih, Whh, pre32, units);
    fc_kernel<<<1024, 256, 0, stream>>>(units, Wfc, bfc, out);
  } else {
    sentinel_kernel<<<(out_size + 255)/256, 256, 0, stream>>>(out, out_size);
  }
}